// Round 9
// baseline (3158.548 us; speedup 1.0000x reference)
//
#include <hip/hip_runtime.h>

#define V_NODES 30000
#define DIM 300
#define KP 320            // padded K stride (shorts) for bf16 planes
#define NE 960000
#define NDOCS 8192
#define DLEN 64
#define CM 10000          // QKV chunk rows (30000 = 3*10000)
#define NQKV 900

typedef float f32x4 __attribute__((ext_vector_type(4)));
typedef short bf16x8 __attribute__((ext_vector_type(8)));

// float -> bf16 (RTNE) bit pattern
__device__ __forceinline__ unsigned short f2bf(float x) {
    unsigned u = __float_as_uint(x);
    unsigned r = (u + 0x7FFFu + ((u >> 16) & 1u)) >> 16;
    return (unsigned short)r;
}
__device__ __forceinline__ float bf2f(unsigned short h) {
    return __uint_as_float(((unsigned)h) << 16);
}

// ---------------------------------------------------------------------------
// bf16 MFMA GEMM: A [M][KP] bf16, B [N][KP] bf16 (B pre-transposed), both
// zero-padded in k.  Output fp32 Cf or bf16 Cb (one non-null), stride ldc.
// Epilogue: v = acc*rowscale[r] + bias[c].
// Tile 128x128, 256 thr = 4 waves (2x2), wave 64x64 = 4x4 frags of 16x16x32.
// LDS [kslot][row][8]: 16-lane frag reads are 256B contiguous (conflict-free).
// ---------------------------------------------------------------------------
#define GBM 128
#define GBN 128
#define KTILES (KP / 32)   // 10

__global__ __launch_bounds__(256) void bgemm_kernel(
    const unsigned short* __restrict__ Ab, const unsigned short* __restrict__ Bb,
    float* __restrict__ Cf, unsigned short* __restrict__ Cb, int M, int N, int ldc,
    const float* __restrict__ bias, const float* __restrict__ rowscale)
{
    __shared__ short As[4][GBM][8];   // [kslot][row][8]  8 KB
    __shared__ short Bs[4][GBN][8];

    const int tid = threadIdx.x;
    const int bm = blockIdx.y * GBM, bn = blockIdx.x * GBN;
    const int l = tid & 63, w = tid >> 6;
    const int wr = w >> 1, wc = w & 1;
    const int lk = l >> 4, lr = l & 15;

    const int srow = tid >> 1;           // staged row (A) / col-row (B)
    const int sc0  = (tid & 1) * 2;      // kslot pair base: 0 or 2

    const bool avld = (bm + srow) < M;
    const bool bvld = (bn + srow) < N;
    const unsigned short* ap = Ab + (size_t)(bm + srow) * KP + sc0 * 8;
    const unsigned short* bp = Bb + (size_t)(bn + srow) * KP + sc0 * 8;

    f32x4 acc[4][4];
#pragma unroll
    for (int m = 0; m < 4; m++)
#pragma unroll
        for (int n = 0; n < 4; n++) acc[m][n] = (f32x4){0.f, 0.f, 0.f, 0.f};

    const bf16x8 zz = (bf16x8){0,0,0,0,0,0,0,0};

    for (int kt = 0; kt < KTILES; kt++) {
        const int k0 = kt * 32;
        bf16x8 va0 = avld ? *(const bf16x8*)(ap + k0)     : zz;
        bf16x8 va1 = avld ? *(const bf16x8*)(ap + k0 + 8) : zz;
        bf16x8 vb0 = bvld ? *(const bf16x8*)(bp + k0)     : zz;
        bf16x8 vb1 = bvld ? *(const bf16x8*)(bp + k0 + 8) : zz;

        *(bf16x8*)&As[sc0    ][srow][0] = va0;
        *(bf16x8*)&As[sc0 + 1][srow][0] = va1;
        *(bf16x8*)&Bs[sc0    ][srow][0] = vb0;
        *(bf16x8*)&Bs[sc0 + 1][srow][0] = vb1;
        __syncthreads();

        bf16x8 a[4], b[4];
#pragma unroll
        for (int m = 0; m < 4; m++)
            a[m] = *(const bf16x8*)&As[lk][wr * 64 + m * 16 + lr][0];
#pragma unroll
        for (int n = 0; n < 4; n++)
            b[n] = *(const bf16x8*)&Bs[lk][wc * 64 + n * 16 + lr][0];
#pragma unroll
        for (int m = 0; m < 4; m++)
#pragma unroll
            for (int n = 0; n < 4; n++)
                acc[m][n] = __builtin_amdgcn_mfma_f32_16x16x32_bf16(a[m], b[n], acc[m][n], 0, 0, 0);
        __syncthreads();
    }

    // epilogue: C/D layout col=lane&15, row=(lane>>4)*4+j  [verified r3]
#pragma unroll
    for (int n = 0; n < 4; n++) {
        int gcol = bn + wc * 64 + n * 16 + lr;
        if (gcol >= N) continue;
        float bc = bias ? bias[gcol] : 0.f;
#pragma unroll
        for (int m = 0; m < 4; m++) {
            int rbase = bm + wr * 64 + m * 16 + lk * 4;
#pragma unroll
            for (int j = 0; j < 4; j++) {
                int grow = rbase + j;
                if (grow >= M) continue;
                float vv = acc[m][n][j];
                if (rowscale) vv *= rowscale[grow];
                vv += bc;
                if (Cf) Cf[(size_t)grow * ldc + gcol] = vv;
                else    Cb[(size_t)grow * ldc + gcol] = f2bf(vv);
            }
        }
    }
}

// ---------------------------------------------------------------------------
// fp32 GEMM for small shapes (K % 20 == 0).
// epilogue: v = acc + bias[c] + rowv[r]*colv[c]
// ---------------------------------------------------------------------------
#define BM 128
#define BN 64
#define BK 20

__global__ __launch_bounds__(256) void sgemm_kernel(
    const float* __restrict__ A, const float* __restrict__ B, float* __restrict__ C,
    int M, int N, int K, const float* __restrict__ bias,
    const float* __restrict__ rowv, const float* __restrict__ colv)
{
    __shared__ float Asm[BK][BM + 4];
    __shared__ float Bsm[BK][BN + 4];
    const int tid = threadIdx.x;
    const int bm = blockIdx.y * BM, bn = blockIdx.x * BN;
    const int tx = tid & 15, ty = tid >> 4;

    float acc[8][4];
#pragma unroll
    for (int i = 0; i < 8; i++)
#pragma unroll
        for (int j = 0; j < 4; j++) acc[i][j] = 0.f;

    const int arow = tid >> 1;
    const int akk0 = (tid & 1) * 10;
    const int bnl  = tid & 63;
    const int bkr  = tid >> 6;

    for (int k0 = 0; k0 < K; k0 += BK) {
        {
            int gr = bm + arow;
            if (gr < M) {
                const float* ap = A + (size_t)gr * K + k0 + akk0;
#pragma unroll
                for (int j = 0; j < 10; j++) Asm[akk0 + j][arow] = ap[j];
            } else {
#pragma unroll
                for (int j = 0; j < 10; j++) Asm[akk0 + j][arow] = 0.f;
            }
        }
        {
            int gn = bn + bnl;
            bool nin = gn < N;
#pragma unroll
            for (int p = 0; p < 5; p++) {
                int kk = p * 4 + bkr;
                Bsm[kk][bnl] = nin ? B[(size_t)(k0 + kk) * N + gn] : 0.f;
            }
        }
        __syncthreads();
#pragma unroll
        for (int kk = 0; kk < BK; kk++) {
            float4 a0 = *(const float4*)&Asm[kk][ty * 8];
            float4 a1 = *(const float4*)&Asm[kk][ty * 8 + 4];
            float4 b  = *(const float4*)&Bsm[kk][tx * 4];
            float av[8] = {a0.x, a0.y, a0.z, a0.w, a1.x, a1.y, a1.z, a1.w};
            float bvv[4] = {b.x, b.y, b.z, b.w};
#pragma unroll
            for (int i = 0; i < 8; i++)
#pragma unroll
                for (int j = 0; j < 4; j++)
                    acc[i][j] = fmaf(av[i], bvv[j], acc[i][j]);
        }
        __syncthreads();
    }
#pragma unroll
    for (int i = 0; i < 8; i++) {
        int r = bm + ty * 8 + i;
        if (r >= M) continue;
        float rv = rowv ? rowv[r] : 0.f;
#pragma unroll
        for (int j = 0; j < 4; j++) {
            int c = bn + tx * 4 + j;
            if (c < N) {
                float v = acc[i][j];
                if (bias) v += bias[c];
                if (rowv) v += rv * colv[c];
                C[(size_t)r * N + c] = v;
            }
        }
    }
}

// ---------------------------------------------------------------------------
// Fused graph prep (blockIdx.y selects branch)
// ---------------------------------------------------------------------------
__global__ void degree3_kernel(const int* s0, const int* d0, const int* s1, const int* d1,
                               const int* s2, const int* d2, int* __restrict__ degs)
{
    int e = blockIdx.x * blockDim.x + threadIdx.x;
    if (e >= NE) return;
    int br = blockIdx.y;
    const int* src = (br == 0) ? s0 : (br == 1) ? s1 : s2;
    const int* dst = (br == 0) ? d0 : (br == 1) ? d1 : d2;
    int* deg0 = degs + br * 2 * V_NODES;
    int* deg1 = deg0 + V_NODES;
    atomicAdd(&deg0[src[e]], 1);
    atomicAdd(&deg1[dst[e]], 1);
}

__global__ void nsnd3_kernel(const int* __restrict__ degs, float* __restrict__ ns3,
                             float* __restrict__ nd3, float* __restrict__ ndns3)
{
    int i = blockIdx.x * blockDim.x + threadIdx.x;
    if (i >= V_NODES) return;
    int br = blockIdx.y;
    const int* deg0 = degs + br * 2 * V_NODES;
    const int* deg1 = deg0 + V_NODES;
    float a = rsqrtf((float)max(deg0[i], 1));
    float b = rsqrtf((float)max(deg1[i], 1));
    ns3[br * V_NODES + i] = a;
    nd3[br * V_NODES + i] = b;
    ndns3[br * V_NODES + i] = a * b;
}

// grid = 3 blocks of 1024; each thread owns SCAN_E contiguous elements
#define SCAN_E 30
__global__ void scan3_kernel(const int* __restrict__ degs, int* __restrict__ row_ptr3)
{
    __shared__ int ssum[1024];
    const int br = blockIdx.x;
    const int* deg = degs + br * 2 * V_NODES + V_NODES;   // deg_in
    int* row_ptr = row_ptr3 + br * (V_NODES + 1);
    const int t = threadIdx.x;
    const int base = t * SCAN_E;
    int loc[SCAN_E];
    int s = 0;
#pragma unroll
    for (int j = 0; j < SCAN_E; j++) {
        int i = base + j;
        int d = (i < V_NODES) ? deg[i] : 0;
        loc[j] = s; s += d;
    }
    ssum[t] = s;
    __syncthreads();
    for (int off = 1; off < 1024; off <<= 1) {
        int x = (t >= off) ? ssum[t - off] : 0;
        __syncthreads();
        ssum[t] += x;
        __syncthreads();
    }
    int carry = (t > 0) ? ssum[t - 1] : 0;
#pragma unroll
    for (int j = 0; j < SCAN_E; j++) {
        int i = base + j;
        if (i < V_NODES) row_ptr[i] = carry + loc[j];
    }
    if (t == 1023) row_ptr[V_NODES] = ssum[1023];
}

__global__ void fill3_kernel(const int* s0, const int* d0, const int* s1, const int* d1,
                             const int* s2, const int* d2, const int* __restrict__ row_ptr3,
                             int* __restrict__ cursors, int* __restrict__ col3)
{
    int e = blockIdx.x * blockDim.x + threadIdx.x;
    if (e >= NE) return;
    int br = blockIdx.y;
    const int* src = (br == 0) ? s0 : (br == 1) ? s1 : s2;
    const int* dst = (br == 0) ? d0 : (br == 1) ? d1 : d2;
    const int* row_ptr = row_ptr3 + br * (V_NODES + 1);
    int* cursor = cursors + br * V_NODES;
    int* col = col3 + (size_t)br * NE;
    int d = dst[e];
    int p = atomicAdd(&cursor[d], 1);
    col[row_ptr[d] + p] = src[e];
}

// dhat[v] = nd[v] * sum_{in-edges} ns[src]
__global__ void dhat3_kernel(const int* __restrict__ row_ptr3, const int* __restrict__ col3,
                             const float* __restrict__ ns3, const float* __restrict__ nd3,
                             float* __restrict__ dhat3)
{
    int v = blockIdx.x * blockDim.x + threadIdx.x;
    if (v >= V_NODES) return;
    int br = blockIdx.y;
    const int* row_ptr = row_ptr3 + br * (V_NODES + 1);
    const int* col = col3 + (size_t)br * NE;
    const float* ns = ns3 + br * V_NODES;
    float s = 0.f;
    int e0 = row_ptr[v], e1 = row_ptr[v + 1];
    for (int e = e0; e < e1; e++) s += ns[col[e]];
    dhat3[br * V_NODES + v] = s * nd3[br * V_NODES + v];
}

// ---------------------------------------------------------------------------
// Aggregation over bf16 rows: out_b[v,:] = bf16( scalev[v]*(sum_in hb[src,:])
//   [+ bias] [+ r1row[v]*r1col] [+ residual_f32] ), KP-stride, pad zeroed.
// 320 threads: one bf16 column each.
// ---------------------------------------------------------------------------
__global__ __launch_bounds__(320) void agg_kernel(
    const unsigned short* __restrict__ hb, const int* __restrict__ row_ptr,
    const int* __restrict__ col, const float* __restrict__ scalev,
    const float* __restrict__ bias, const float* __restrict__ r1row,
    const float* __restrict__ r1col, const float* __restrict__ residual,
    unsigned short* __restrict__ ob)
{
    int v = blockIdx.x;
    int t = threadIdx.x;
    int beg = row_ptr[v], end = row_ptr[v + 1];
    float vv = 0.f;
    if (t < DIM) {
        float a = 0.f;
        for (int e = beg; e < end; e++)
            a += bf2f(hb[(size_t)col[e] * KP + t]);
        vv = a * scalev[v];
        if (bias) vv += bias[t];
        if (r1row) vv += r1row[v] * r1col[t];
        if (residual) vv += residual[(size_t)v * DIM + t];
    }
    ob[(size_t)v * KP + t] = f2bf(vv);
}

// ---------------------------------------------------------------------------
// bf16 plane builders
// ---------------------------------------------------------------------------
// X [M][300] fp32 -> [M][KP] bf16 (zero-padded)
__global__ void splitb_a_kernel(const float* __restrict__ X, unsigned short* __restrict__ ob)
{
    int v = blockIdx.x;
    int k = threadIdx.x;        // 320 threads
    float x = (k < DIM) ? X[(size_t)v * DIM + k] : 0.f;
    ob[(size_t)v * KP + k] = f2bf(x);
}

// W [300][ncols] fp32 -> transposed rows (col0+n): [*][KP] bf16
__global__ void splitb_w_kernel(const float* __restrict__ W, int ncols, int col0,
                                unsigned short* __restrict__ ob)
{
    int n = blockIdx.x;
    int k = threadIdx.x;        // 320 threads
    float x = (k < DIM) ? W[(size_t)k * ncols + n] : 0.f;
    ob[(size_t)(col0 + n) * KP + k] = f2bf(x);
}

__global__ void concat3_kernel(const float* __restrict__ a, const float* __restrict__ b,
                               const float* __restrict__ c, float* __restrict__ o)
{
    int t = blockIdx.x * 256 + threadIdx.x;
    if (t >= NQKV) return;
    o[t] = (t < 300) ? a[t] : ((t < 600) ? b[t - 300] : c[t - 600]);
}

// ---------------------------------------------------------------------------
// 30-head attention over 3 views, folded mean over q-positions.
// QKVb bf16: [3][cm][900] rows = q|k|v.  Writes om_b rows [r0, r0+cm), KP stride.
// ---------------------------------------------------------------------------
__global__ __launch_bounds__(256) void attn_kernel(
    const unsigned short* __restrict__ QKVb, unsigned short* __restrict__ omb,
    int cm, int r0)
{
    int t = blockIdx.x * 256 + threadIdx.x;
    if (t >= cm * 30) return;
    int i = t / 30, h = t - i * 30;
    int off = h * 10;
    float q[3][10], k[3][10], v[3][10];
#pragma unroll
    for (int s = 0; s < 3; s++) {
        const unsigned short* base = QKVb + ((size_t)s * cm + i) * NQKV;
#pragma unroll
        for (int d = 0; d < 10; d++) {
            q[s][d] = bf2f(base[off + d]);
            k[s][d] = bf2f(base[300 + off + d]);
            v[s][d] = bf2f(base[600 + off + d]);
        }
    }
    const float scale = 0.31622776601683794f;  // 1/sqrt(10)
    float wgt[3] = {0.f, 0.f, 0.f};
#pragma unroll
    for (int qi = 0; qi < 3; qi++) {
        float sc[3];
#pragma unroll
        for (int ki = 0; ki < 3; ki++) {
            float s_ = 0.f;
#pragma unroll
            for (int d = 0; d < 10; d++) s_ = fmaf(q[qi][d], k[ki][d], s_);
            sc[ki] = s_ * scale;
        }
        float m = fmaxf(sc[0], fmaxf(sc[1], sc[2]));
        float e0 = expf(sc[0] - m), e1 = expf(sc[1] - m), e2 = expf(sc[2] - m);
        float inv = 1.f / (e0 + e1 + e2);
        wgt[0] += e0 * inv; wgt[1] += e1 * inv; wgt[2] += e2 * inv;
    }
    unsigned short* op = omb + (size_t)(r0 + i) * KP + off;
#pragma unroll
    for (int d = 0; d < 10; d++)
        op[d] = f2bf((wgt[0] * v[0][d] + wgt[1] * v[1][d] + wgt[2] * v[2][d]) * (1.f / 3.f));
}

// DM[d,:] = (1/64) * sum over valid tokens of om_b[idx,:];  DC[d] = cnt/64
__global__ __launch_bounds__(320) void docmean_kernel(
    const unsigned short* __restrict__ omb, const int* __restrict__ adj,
    float* __restrict__ DM, float* __restrict__ DC)
{
    int d = blockIdx.x;
    int t = threadIdx.x;
    float a = 0.f;
    int cnt = 0;
    for (int l = 0; l < DLEN; l++) {
        int idx = adj[d * DLEN + l];
        if (idx < V_NODES) {
            cnt++;
            if (t < DIM) a += bf2f(omb[(size_t)idx * KP + t]);
        }
    }
    if (t < DIM) DM[(size_t)d * DIM + t] = a * (1.f / 64.f);
    if (t == 0) DC[d] = (float)cnt * (1.f / 64.f);
}

// ---------------------------------------------------------------------------
extern "C" void kernel_launch(void* const* d_in, const int* in_sizes, int n_in,
                              void* d_out, int out_size, void* d_ws, size_t ws_size,
                              hipStream_t stream)
{
    const int* adj = (const int*)d_in[0];
    const int* srcs[3] = {(const int*)d_in[1], (const int*)d_in[3], (const int*)d_in[5]};
    const int* dsts[3] = {(const int*)d_in[2], (const int*)d_in[4], (const int*)d_in[6]};
    const float* emb = (const float*)d_in[8];
    const float* W1[3] = {(const float*)d_in[9],  (const float*)d_in[13], (const float*)d_in[17]};
    const float* b1[3] = {(const float*)d_in[10], (const float*)d_in[14], (const float*)d_in[18]};
    const float* W2[3] = {(const float*)d_in[11], (const float*)d_in[15], (const float*)d_in[19]};
    const float* b2[3] = {(const float*)d_in[12], (const float*)d_in[16], (const float*)d_in[20]};
    const float* Wq = (const float*)d_in[21], *bq = (const float*)d_in[22];
    const float* Wk = (const float*)d_in[23], *bk = (const float*)d_in[24];
    const float* Wv = (const float*)d_in[25], *bv = (const float*)d_in[26];
    const float* Wo = (const float*)d_in[27], *bo = (const float*)d_in[28];
    const float* Wd = (const float*)d_in[29], *bd = (const float*)d_in[30];
    const float* Wfc = (const float*)d_in[31], *bfc = (const float*)d_in[32];
    float* out = (float*)d_out;

    // ---- workspace carve ----
    char* p = (char*)d_ws;
    auto alloc = [&](size_t bytes) { void* r = (void*)p; p += (bytes + 255) & ~(size_t)255; return r; };
    // [embs_b | T1b | Tmid_b] contiguous 57.6 MB; QKVb (54 MB) aliases it post-GCN
    unsigned short* embs_b = (unsigned short*)alloc((size_t)V_NODES * KP * 2);  // 19.2 MB
    unsigned short* T1b    = (unsigned short*)alloc((size_t)V_NODES * KP * 2);  // 19.2 MB
    unsigned short* Tmidb  = (unsigned short*)alloc((size_t)V_NODES * KP * 2);  // 19.2 MB
    unsigned short* QKVb   = embs_b;   // [3][CM][900] bf16 = 54 MB <= 57.6 MB

    unsigned short* omb = (unsigned short*)alloc((size_t)V_NODES * KP * 2);     // 19.2 MB

    float* ns3   = (float*)alloc((size_t)3 * V_NODES * 4);
    float* nd3   = (float*)alloc((size_t)3 * V_NODES * 4);
    float* ndns3 = (float*)alloc((size_t)3 * V_NODES * 4);
    float* dhat3 = (float*)alloc((size_t)3 * V_NODES * 4);
    int* degs    = (int*)alloc((size_t)9 * V_NODES * 4);   // deg0|deg1 (x3) + cursors(x3)
    int* cursors = degs + 6 * V_NODES;
    int* row_ptr3 = (int*)alloc((size_t)3 * (V_NODES + 1) * 4);
    int* col3     = (int*)alloc((size_t)3 * NE * 4);

    float* Wdf   = (float*)alloc(300 * 20 * 4);
    float* Wcomb = (float*)alloc(300 * 20 * 4);
    float* v1    = (float*)alloc(20 * 4);
    float* v2    = (float*)alloc(20 * 4);
    float* b1w2  = (float*)alloc(300 * 4);
    float* bqkv  = (float*)alloc(NQKV * 4);
    float* W12   = (float*)alloc(300 * 300 * 4);
    unsigned short* W12b  = (unsigned short*)alloc(300 * KP * 2);
    unsigned short* Wqkvb = (unsigned short*)alloc((size_t)NQKV * KP * 2);

    unsigned short* Bvs_b[3];
    for (int i = 0; i < 3; i++)
        Bvs_b[i] = (unsigned short*)alloc((size_t)V_NODES * KP * 2);            // 3x19.2 MB
    float* DM = (float*)Bvs_b[0];   // [NDOCS][300] fp32 = 9.8 MB (Bvs free post-QKV)
    float* DC = (float*)Bvs_b[1];

    auto bgemm = [&](const unsigned short* ab, const unsigned short* bb,
                     float* cf, unsigned short* cb, int M, int N, int ldc,
                     const float* bias, const float* rowscale) {
        dim3 grid((N + GBN - 1) / GBN, (M + GBM - 1) / GBM);
        hipLaunchKernelGGL(bgemm_kernel, grid, dim3(256), 0, stream,
                           ab, bb, cf, cb, M, N, ldc, bias, rowscale);
    };
    auto sgemm = [&](const float* A, const float* B, float* C, int M, int N, int K,
                     const float* bias, const float* rowv = nullptr, const float* colv = nullptr) {
        dim3 grid((N + BN - 1) / BN, (M + BM - 1) / BM);
        hipLaunchKernelGGL(sgemm_kernel, grid, dim3(256), 0, stream,
                           A, B, C, M, N, K, bias, rowv, colv);
    };

    const int EB = (NE + 255) / 256;
    const int VB = (V_NODES + 255) / 256;

    // ---- one-time prep ----
    sgemm(Wd, Wfc, Wdf, DIM, 20, DIM, nullptr);            // Wd@Wfc
    sgemm(Wo, Wdf, Wcomb, DIM, 20, DIM, nullptr);          // Wo@Wd@Wfc
    sgemm(bo, Wdf, v1, 1, 20, DIM, nullptr);               // bo@Wd@Wfc
    sgemm(bd, Wfc, v2, 1, 20, DIM, bfc);                   // bd@Wfc+bfc
    hipLaunchKernelGGL(concat3_kernel, dim3(4), dim3(256), 0, stream, bq, bk, bv, bqkv);
    hipLaunchKernelGGL(splitb_w_kernel, dim3(300), dim3(KP), 0, stream, Wq, 300, 0,   Wqkvb);
    hipLaunchKernelGGL(splitb_w_kernel, dim3(300), dim3(KP), 0, stream, Wk, 300, 300, Wqkvb);
    hipLaunchKernelGGL(splitb_w_kernel, dim3(300), dim3(KP), 0, stream, Wv, 300, 600, Wqkvb);
    hipLaunchKernelGGL(splitb_a_kernel, dim3(V_NODES), dim3(KP), 0, stream, emb, embs_b);

    // ---- fused graph prep for all 3 branches ----
    hipMemsetAsync(degs, 0, (size_t)9 * V_NODES * 4, stream);
    hipLaunchKernelGGL(degree3_kernel, dim3(EB, 3), dim3(256), 0, stream,
                       srcs[0], dsts[0], srcs[1], dsts[1], srcs[2], dsts[2], degs);
    hipLaunchKernelGGL(nsnd3_kernel, dim3(VB, 3), dim3(256), 0, stream, degs, ns3, nd3, ndns3);
    hipLaunchKernelGGL(scan3_kernel, dim3(3), dim3(1024), 0, stream, degs, row_ptr3);
    hipLaunchKernelGGL(fill3_kernel, dim3(EB, 3), dim3(256), 0, stream,
                       srcs[0], dsts[0], srcs[1], dsts[1], srcs[2], dsts[2],
                       row_ptr3, cursors, col3);
    hipLaunchKernelGGL(dhat3_kernel, dim3(VB, 3), dim3(256), 0, stream,
                       row_ptr3, col3, ns3, nd3, dhat3);

    // ---- three GCN branches (layers folded: nd⊙A(ndns⊙A(ns⊙(X W12))) + dhat⊗(b1W2) + b2 + X) ----
    for (int br = 0; br < 3; br++) {
        const int* row_ptr = row_ptr3 + br * (V_NODES + 1);
        const int* col = col3 + (size_t)br * NE;
        const float* ns = ns3 + br * V_NODES;
        const float* nd = nd3 + br * V_NODES;
        const float* ndns = ndns3 + br * V_NODES;
        const float* dhat = dhat3 + br * V_NODES;

        sgemm(W1[br], W2[br], W12, DIM, DIM, DIM, nullptr);           // W12 = W1@W2
        sgemm(b1[br], W2[br], b1w2, 1, DIM, DIM, nullptr);            // b1@W2
        hipLaunchKernelGGL(splitb_w_kernel, dim3(300), dim3(KP), 0, stream, W12, 300, 0, W12b);

        // T1b = bf16( ns ⊙ (emb @ W12) )
        bgemm(embs_b, W12b, nullptr, T1b, V_NODES, DIM, KP, nullptr, ns);
        // Tmidb = bf16( ndns ⊙ A(T1b) )
        hipLaunchKernelGGL(agg_kernel, dim3(V_NODES), dim3(320), 0, stream,
                           T1b, row_ptr, col, ndns,
                           (const float*)nullptr, (const float*)nullptr,
                           (const float*)nullptr, (const float*)nullptr, Tmidb);
        // Bvs[br] = bf16( nd ⊙ A(Tmidb) + dhat⊗b1w2 + b2 + emb )
        hipLaunchKernelGGL(agg_kernel, dim3(V_NODES), dim3(320), 0, stream,
                           Tmidb, row_ptr, col, nd, b2[br], dhat, b1w2, emb, Bvs_b[br]);
    }

    // ---- QKV + attention (chunked; QKVb aliases embs/T1b/Tmidb, all dead now) ----
    for (int c = 0; c < V_NODES / CM; c++) {
        int r0 = c * CM;
        for (int s = 0; s < 3; s++) {
            bgemm(Bvs_b[s] + (size_t)r0 * KP, Wqkvb,
                  nullptr, QKVb + (size_t)s * CM * NQKV, CM, NQKV, NQKV, bqkv, nullptr);
        }
        hipLaunchKernelGGL(attn_kernel, dim3((CM * 30 + 255) / 256), dim3(256), 0, stream,
                           QKVb, omb, CM, r0);
    }

    // ---- doc pipeline (folded tail) ----
    hipLaunchKernelGGL(docmean_kernel, dim3(NDOCS), dim3(320), 0, stream, omb, adj, DM, DC);
    sgemm(DM, Wcomb, out, NDOCS, 20, DIM, v2, DC, v1);   // out = DM@Wcomb + DC⊗v1 + v2
}

// Round 10
// 1990.751 us; speedup vs baseline: 1.5866x; 1.5866x over previous
//
#include <hip/hip_runtime.h>

#define V_NODES 30000
#define DIM 300
#define KP 320            // padded K stride (shorts) for bf16 planes
#define NE 960000
#define NDOCS 8192
#define DLEN 64
#define CM 10000          // QKV chunk rows (30000 = 3*10000)
#define NQKV 900
#define AST 8             // edge stripes in agg/docmean

typedef float f32x4 __attribute__((ext_vector_type(4)));
typedef short bf16x8 __attribute__((ext_vector_type(8)));
typedef unsigned int uint4v __attribute__((ext_vector_type(4)));

// float -> bf16 (RTNE) bit pattern
__device__ __forceinline__ unsigned short f2bf(float x) {
    unsigned u = __float_as_uint(x);
    unsigned r = (u + 0x7FFFu + ((u >> 16) & 1u)) >> 16;
    return (unsigned short)r;
}
__device__ __forceinline__ float bf2f(unsigned short h) {
    return __uint_as_float(((unsigned)h) << 16);
}

// ---------------------------------------------------------------------------
// bf16 MFMA GEMM: A [M][KP] bf16, B [N][KP] bf16 (B pre-transposed), both
// zero-padded in k.  Output fp32 Cf or bf16 Cb (one non-null), stride ldc.
// Epilogue: v = acc*rowscale[r] + bias[c].
// Tile 128x128, 256 thr = 4 waves (2x2), wave 64x64 = 4x4 frags of 16x16x32.
// ---------------------------------------------------------------------------
#define GBM 128
#define GBN 128
#define KTILES (KP / 32)   // 10

__global__ __launch_bounds__(256) void bgemm_kernel(
    const unsigned short* __restrict__ Ab, const unsigned short* __restrict__ Bb,
    float* __restrict__ Cf, unsigned short* __restrict__ Cb, int M, int N, int ldc,
    const float* __restrict__ bias, const float* __restrict__ rowscale)
{
    __shared__ short As[4][GBM][8];   // [kslot][row][8]  8 KB
    __shared__ short Bs[4][GBN][8];

    const int tid = threadIdx.x;
    const int bm = blockIdx.y * GBM, bn = blockIdx.x * GBN;
    const int l = tid & 63, w = tid >> 6;
    const int wr = w >> 1, wc = w & 1;
    const int lk = l >> 4, lr = l & 15;

    const int srow = tid >> 1;           // staged row (A) / col-row (B)
    const int sc0  = (tid & 1) * 2;      // kslot pair base: 0 or 2

    const bool avld = (bm + srow) < M;
    const bool bvld = (bn + srow) < N;
    const unsigned short* ap = Ab + (size_t)(bm + srow) * KP + sc0 * 8;
    const unsigned short* bp = Bb + (size_t)(bn + srow) * KP + sc0 * 8;

    f32x4 acc[4][4];
#pragma unroll
    for (int m = 0; m < 4; m++)
#pragma unroll
        for (int n = 0; n < 4; n++) acc[m][n] = (f32x4){0.f, 0.f, 0.f, 0.f};

    const bf16x8 zz = (bf16x8){0,0,0,0,0,0,0,0};

    for (int kt = 0; kt < KTILES; kt++) {
        const int k0 = kt * 32;
        bf16x8 va0 = avld ? *(const bf16x8*)(ap + k0)     : zz;
        bf16x8 va1 = avld ? *(const bf16x8*)(ap + k0 + 8) : zz;
        bf16x8 vb0 = bvld ? *(const bf16x8*)(bp + k0)     : zz;
        bf16x8 vb1 = bvld ? *(const bf16x8*)(bp + k0 + 8) : zz;

        *(bf16x8*)&As[sc0    ][srow][0] = va0;
        *(bf16x8*)&As[sc0 + 1][srow][0] = va1;
        *(bf16x8*)&Bs[sc0    ][srow][0] = vb0;
        *(bf16x8*)&Bs[sc0 + 1][srow][0] = vb1;
        __syncthreads();

        bf16x8 a[4], b[4];
#pragma unroll
        for (int m = 0; m < 4; m++)
            a[m] = *(const bf16x8*)&As[lk][wr * 64 + m * 16 + lr][0];
#pragma unroll
        for (int n = 0; n < 4; n++)
            b[n] = *(const bf16x8*)&Bs[lk][wc * 64 + n * 16 + lr][0];
#pragma unroll
        for (int m = 0; m < 4; m++)
#pragma unroll
            for (int n = 0; n < 4; n++)
                acc[m][n] = __builtin_amdgcn_mfma_f32_16x16x32_bf16(a[m], b[n], acc[m][n], 0, 0, 0);
        __syncthreads();
    }

    // epilogue: C/D layout col=lane&15, row=(lane>>4)*4+j  [verified r3]
#pragma unroll
    for (int n = 0; n < 4; n++) {
        int gcol = bn + wc * 64 + n * 16 + lr;
        if (gcol >= N) continue;
        float bc = bias ? bias[gcol] : 0.f;
#pragma unroll
        for (int m = 0; m < 4; m++) {
            int rbase = bm + wr * 64 + m * 16 + lk * 4;
#pragma unroll
            for (int j = 0; j < 4; j++) {
                int grow = rbase + j;
                if (grow >= M) continue;
                float vv = acc[m][n][j];
                if (rowscale) vv *= rowscale[grow];
                vv += bc;
                if (Cf) Cf[(size_t)grow * ldc + gcol] = vv;
                else    Cb[(size_t)grow * ldc + gcol] = f2bf(vv);
            }
        }
    }
}

// ---------------------------------------------------------------------------
// fp32 GEMM for small shapes (K % 20 == 0).
// epilogue: v = acc + bias[c] + rowv[r]*colv[c]
// ---------------------------------------------------------------------------
#define BM 128
#define BN 64
#define BK 20

__global__ __launch_bounds__(256) void sgemm_kernel(
    const float* __restrict__ A, const float* __restrict__ B, float* __restrict__ C,
    int M, int N, int K, const float* __restrict__ bias,
    const float* __restrict__ rowv, const float* __restrict__ colv)
{
    __shared__ float Asm[BK][BM + 4];
    __shared__ float Bsm[BK][BN + 4];
    const int tid = threadIdx.x;
    const int bm = blockIdx.y * BM, bn = blockIdx.x * BN;
    const int tx = tid & 15, ty = tid >> 4;

    float acc[8][4];
#pragma unroll
    for (int i = 0; i < 8; i++)
#pragma unroll
        for (int j = 0; j < 4; j++) acc[i][j] = 0.f;

    const int arow = tid >> 1;
    const int akk0 = (tid & 1) * 10;
    const int bnl  = tid & 63;
    const int bkr  = tid >> 6;

    for (int k0 = 0; k0 < K; k0 += BK) {
        {
            int gr = bm + arow;
            if (gr < M) {
                const float* ap = A + (size_t)gr * K + k0 + akk0;
#pragma unroll
                for (int j = 0; j < 10; j++) Asm[akk0 + j][arow] = ap[j];
            } else {
#pragma unroll
                for (int j = 0; j < 10; j++) Asm[akk0 + j][arow] = 0.f;
            }
        }
        {
            int gn = bn + bnl;
            bool nin = gn < N;
#pragma unroll
            for (int p = 0; p < 5; p++) {
                int kk = p * 4 + bkr;
                Bsm[kk][bnl] = nin ? B[(size_t)(k0 + kk) * N + gn] : 0.f;
            }
        }
        __syncthreads();
#pragma unroll
        for (int kk = 0; kk < BK; kk++) {
            float4 a0 = *(const float4*)&Asm[kk][ty * 8];
            float4 a1 = *(const float4*)&Asm[kk][ty * 8 + 4];
            float4 b  = *(const float4*)&Bsm[kk][tx * 4];
            float av[8] = {a0.x, a0.y, a0.z, a0.w, a1.x, a1.y, a1.z, a1.w};
            float bvv[4] = {b.x, b.y, b.z, b.w};
#pragma unroll
            for (int i = 0; i < 8; i++)
#pragma unroll
                for (int j = 0; j < 4; j++)
                    acc[i][j] = fmaf(av[i], bvv[j], acc[i][j]);
        }
        __syncthreads();
    }
#pragma unroll
    for (int i = 0; i < 8; i++) {
        int r = bm + ty * 8 + i;
        if (r >= M) continue;
        float rv = rowv ? rowv[r] : 0.f;
#pragma unroll
        for (int j = 0; j < 4; j++) {
            int c = bn + tx * 4 + j;
            if (c < N) {
                float v = acc[i][j];
                if (bias) v += bias[c];
                if (rowv) v += rv * colv[c];
                C[(size_t)r * N + c] = v;
            }
        }
    }
}

// ---------------------------------------------------------------------------
// Fused graph prep (blockIdx.y selects branch)
// ---------------------------------------------------------------------------
__global__ void degree3_kernel(const int* s0, const int* d0, const int* s1, const int* d1,
                               const int* s2, const int* d2, int* __restrict__ degs)
{
    int e = blockIdx.x * blockDim.x + threadIdx.x;
    if (e >= NE) return;
    int br = blockIdx.y;
    const int* src = (br == 0) ? s0 : (br == 1) ? s1 : s2;
    const int* dst = (br == 0) ? d0 : (br == 1) ? d1 : d2;
    int* deg0 = degs + br * 2 * V_NODES;
    int* deg1 = deg0 + V_NODES;
    atomicAdd(&deg0[src[e]], 1);
    atomicAdd(&deg1[dst[e]], 1);
}

__global__ void nsnd3_kernel(const int* __restrict__ degs, float* __restrict__ ns3,
                             float* __restrict__ nd3, float* __restrict__ ndns3)
{
    int i = blockIdx.x * blockDim.x + threadIdx.x;
    if (i >= V_NODES) return;
    int br = blockIdx.y;
    const int* deg0 = degs + br * 2 * V_NODES;
    const int* deg1 = deg0 + V_NODES;
    float a = rsqrtf((float)max(deg0[i], 1));
    float b = rsqrtf((float)max(deg1[i], 1));
    ns3[br * V_NODES + i] = a;
    nd3[br * V_NODES + i] = b;
    ndns3[br * V_NODES + i] = a * b;
}

// grid = 3 blocks of 1024; each thread owns SCAN_E contiguous elements
#define SCAN_E 30
__global__ void scan3_kernel(const int* __restrict__ degs, int* __restrict__ row_ptr3)
{
    __shared__ int ssum[1024];
    const int br = blockIdx.x;
    const int* deg = degs + br * 2 * V_NODES + V_NODES;   // deg_in
    int* row_ptr = row_ptr3 + br * (V_NODES + 1);
    const int t = threadIdx.x;
    const int base = t * SCAN_E;
    int loc[SCAN_E];
    int s = 0;
#pragma unroll
    for (int j = 0; j < SCAN_E; j++) {
        int i = base + j;
        int d = (i < V_NODES) ? deg[i] : 0;
        loc[j] = s; s += d;
    }
    ssum[t] = s;
    __syncthreads();
    for (int off = 1; off < 1024; off <<= 1) {
        int x = (t >= off) ? ssum[t - off] : 0;
        __syncthreads();
        ssum[t] += x;
        __syncthreads();
    }
    int carry = (t > 0) ? ssum[t - 1] : 0;
#pragma unroll
    for (int j = 0; j < SCAN_E; j++) {
        int i = base + j;
        if (i < V_NODES) row_ptr[i] = carry + loc[j];
    }
    if (t == 1023) row_ptr[V_NODES] = ssum[1023];
}

__global__ void fill3_kernel(const int* s0, const int* d0, const int* s1, const int* d1,
                             const int* s2, const int* d2, const int* __restrict__ row_ptr3,
                             int* __restrict__ cursors, int* __restrict__ col3)
{
    int e = blockIdx.x * blockDim.x + threadIdx.x;
    if (e >= NE) return;
    int br = blockIdx.y;
    const int* src = (br == 0) ? s0 : (br == 1) ? s1 : s2;
    const int* dst = (br == 0) ? d0 : (br == 1) ? d1 : d2;
    const int* row_ptr = row_ptr3 + br * (V_NODES + 1);
    int* cursor = cursors + br * V_NODES;
    int* col = col3 + (size_t)br * NE;
    int d = dst[e];
    int p = atomicAdd(&cursor[d], 1);
    col[row_ptr[d] + p] = src[e];
}

// dhat[v] = nd[v] * sum_{in-edges} ns[src]
__global__ void dhat3_kernel(const int* __restrict__ row_ptr3, const int* __restrict__ col3,
                             const float* __restrict__ ns3, const float* __restrict__ nd3,
                             float* __restrict__ dhat3)
{
    int v = blockIdx.x * blockDim.x + threadIdx.x;
    if (v >= V_NODES) return;
    int br = blockIdx.y;
    const int* row_ptr = row_ptr3 + br * (V_NODES + 1);
    const int* col = col3 + (size_t)br * NE;
    const float* ns = ns3 + br * V_NODES;
    float s = 0.f;
    int e0 = row_ptr[v], e1 = row_ptr[v + 1];
    for (int e = e0; e < e1; e++) s += ns[col[e]];
    dhat3[br * V_NODES + v] = s * nd3[br * V_NODES + v];
}

// ---------------------------------------------------------------------------
// Aggregation over bf16 rows (MLP-restructured):
// 320 thr = 8 edge-stripes x 40 col-groups; each thread loads uint4 (16B =
// 8 bf16 cols) per edge, unroll x2 -> many loads in flight.  LDS reduce across
// stripes, epilogue identical to before.  out stride KP, pad zeroed.
// ---------------------------------------------------------------------------
__global__ __launch_bounds__(320) void agg_kernel(
    const unsigned short* __restrict__ hb, const int* __restrict__ row_ptr,
    const int* __restrict__ col, const float* __restrict__ scalev,
    const float* __restrict__ bias, const float* __restrict__ r1row,
    const float* __restrict__ r1col, const float* __restrict__ residual,
    unsigned short* __restrict__ ob)
{
    __shared__ float red[AST][KP];   // 10.24 KB
    const int v = blockIdx.x;
    const int t = threadIdx.x;
    const int ce = t / 40;           // stripe 0..7
    const int cc = t % 40;           // col-group (uint4 = 8 shorts)
    const int beg = row_ptr[v], end = row_ptr[v + 1];

    float a[8];
#pragma unroll
    for (int j = 0; j < 8; j++) a[j] = 0.f;

#define ACC8(x)                                                         \
    {                                                                   \
        _Pragma("unroll")                                               \
        for (int w_ = 0; w_ < 4; w_++) {                                \
            unsigned u_ = (x)[w_];                                      \
            a[2*w_]   += __uint_as_float(u_ << 16);                     \
            a[2*w_+1] += __uint_as_float(u_ & 0xFFFF0000u);             \
        }                                                               \
    }

    int e = beg + ce;
    for (; e + AST < end; e += 2 * AST) {
        int c0 = col[e];
        int c1 = col[e + AST];
        uint4v x0 = *(const uint4v*)(hb + (size_t)c0 * KP + cc * 8);
        uint4v x1 = *(const uint4v*)(hb + (size_t)c1 * KP + cc * 8);
        ACC8(x0);
        ACC8(x1);
    }
    if (e < end) {
        int c0 = col[e];
        uint4v x0 = *(const uint4v*)(hb + (size_t)c0 * KP + cc * 8);
        ACC8(x0);
    }
#undef ACC8

#pragma unroll
    for (int j = 0; j < 8; j++) red[ce][cc * 8 + j] = a[j];
    __syncthreads();

    // thread t owns column t
    float s = 0.f;
#pragma unroll
    for (int k = 0; k < AST; k++) s += red[k][t];

    float vv = 0.f;
    if (t < DIM) {
        vv = s * scalev[v];
        if (bias) vv += bias[t];
        if (r1row) vv += r1row[v] * r1col[t];
        if (residual) vv += residual[(size_t)v * DIM + t];
    }
    ob[(size_t)v * KP + t] = f2bf(vv);
}

// ---------------------------------------------------------------------------
// bf16 plane builders
// ---------------------------------------------------------------------------
// X [M][300] fp32 -> [M][KP] bf16 (zero-padded)
__global__ void splitb_a_kernel(const float* __restrict__ X, unsigned short* __restrict__ ob)
{
    int v = blockIdx.x;
    int k = threadIdx.x;        // 320 threads
    float x = (k < DIM) ? X[(size_t)v * DIM + k] : 0.f;
    ob[(size_t)v * KP + k] = f2bf(x);
}

// W [300][ncols] fp32 -> transposed rows (col0+n): [*][KP] bf16
__global__ void splitb_w_kernel(const float* __restrict__ W, int ncols, int col0,
                                unsigned short* __restrict__ ob)
{
    int n = blockIdx.x;
    int k = threadIdx.x;        // 320 threads
    float x = (k < DIM) ? W[(size_t)k * ncols + n] : 0.f;
    ob[(size_t)(col0 + n) * KP + k] = f2bf(x);
}

__global__ void concat3_kernel(const float* __restrict__ a, const float* __restrict__ b,
                               const float* __restrict__ c, float* __restrict__ o)
{
    int t = blockIdx.x * 256 + threadIdx.x;
    if (t >= NQKV) return;
    o[t] = (t < 300) ? a[t] : ((t < 600) ? b[t - 300] : c[t - 600]);
}

// ---------------------------------------------------------------------------
// 30-head attention over 3 views, folded mean over q-positions.
// QKVb bf16: [3][cm][900] rows = q|k|v.  Writes om_b rows [r0, r0+cm), KP stride.
// ---------------------------------------------------------------------------
__global__ __launch_bounds__(256) void attn_kernel(
    const unsigned short* __restrict__ QKVb, unsigned short* __restrict__ omb,
    int cm, int r0)
{
    int t = blockIdx.x * 256 + threadIdx.x;
    if (t >= cm * 30) return;
    int i = t / 30, h = t - i * 30;
    int off = h * 10;
    float q[3][10], k[3][10], v[3][10];
#pragma unroll
    for (int s = 0; s < 3; s++) {
        const unsigned short* base = QKVb + ((size_t)s * cm + i) * NQKV;
#pragma unroll
        for (int d = 0; d < 10; d++) {
            q[s][d] = bf2f(base[off + d]);
            k[s][d] = bf2f(base[300 + off + d]);
            v[s][d] = bf2f(base[600 + off + d]);
        }
    }
    const float scale = 0.31622776601683794f;  // 1/sqrt(10)
    float wgt[3] = {0.f, 0.f, 0.f};
#pragma unroll
    for (int qi = 0; qi < 3; qi++) {
        float sc[3];
#pragma unroll
        for (int ki = 0; ki < 3; ki++) {
            float s_ = 0.f;
#pragma unroll
            for (int d = 0; d < 10; d++) s_ = fmaf(q[qi][d], k[ki][d], s_);
            sc[ki] = s_ * scale;
        }
        float m = fmaxf(sc[0], fmaxf(sc[1], sc[2]));
        float e0 = expf(sc[0] - m), e1 = expf(sc[1] - m), e2 = expf(sc[2] - m);
        float inv = 1.f / (e0 + e1 + e2);
        wgt[0] += e0 * inv; wgt[1] += e1 * inv; wgt[2] += e2 * inv;
    }
    unsigned short* op = omb + (size_t)(r0 + i) * KP + off;
#pragma unroll
    for (int d = 0; d < 10; d++)
        op[d] = f2bf((wgt[0] * v[0][d] + wgt[1] * v[1][d] + wgt[2] * v[2][d]) * (1.f / 3.f));
}

// ---------------------------------------------------------------------------
// docmean (MLP-restructured like agg): DM[d,:] = (1/64)*sum valid tokens of
// om_b[idx,:];  DC[d] = cnt/64.
// ---------------------------------------------------------------------------
__global__ __launch_bounds__(320) void docmean_kernel(
    const unsigned short* __restrict__ omb, const int* __restrict__ adj,
    float* __restrict__ DM, float* __restrict__ DC)
{
    __shared__ float red[AST][KP];
    __shared__ int scnt[AST];
    const int d = blockIdx.x;
    const int t = threadIdx.x;
    const int ce = t / 40;
    const int cc = t % 40;

    float a[8];
#pragma unroll
    for (int j = 0; j < 8; j++) a[j] = 0.f;
    int cnt = 0;

    for (int l = ce; l < DLEN; l += AST) {
        int idx = adj[d * DLEN + l];
        if (idx < V_NODES) {
            cnt++;
            uint4v x = *(const uint4v*)(omb + (size_t)idx * KP + cc * 8);
#pragma unroll
            for (int w_ = 0; w_ < 4; w_++) {
                unsigned u_ = x[w_];
                a[2*w_]   += __uint_as_float(u_ << 16);
                a[2*w_+1] += __uint_as_float(u_ & 0xFFFF0000u);
            }
        }
    }
#pragma unroll
    for (int j = 0; j < 8; j++) red[ce][cc * 8 + j] = a[j];
    if (cc == 0) scnt[ce] = cnt;
    __syncthreads();

    float s = 0.f;
#pragma unroll
    for (int k = 0; k < AST; k++) s += red[k][t];
    if (t < DIM) DM[(size_t)d * DIM + t] = s * (1.f / 64.f);
    if (t == 0) {
        int c = 0;
#pragma unroll
        for (int k = 0; k < AST; k++) c += scnt[k];
        DC[d] = (float)c * (1.f / 64.f);
    }
}

// ---------------------------------------------------------------------------
extern "C" void kernel_launch(void* const* d_in, const int* in_sizes, int n_in,
                              void* d_out, int out_size, void* d_ws, size_t ws_size,
                              hipStream_t stream)
{
    const int* adj = (const int*)d_in[0];
    const int* srcs[3] = {(const int*)d_in[1], (const int*)d_in[3], (const int*)d_in[5]};
    const int* dsts[3] = {(const int*)d_in[2], (const int*)d_in[4], (const int*)d_in[6]};
    const float* emb = (const float*)d_in[8];
    const float* W1[3] = {(const float*)d_in[9],  (const float*)d_in[13], (const float*)d_in[17]};
    const float* b1[3] = {(const float*)d_in[10], (const float*)d_in[14], (const float*)d_in[18]};
    const float* W2[3] = {(const float*)d_in[11], (const float*)d_in[15], (const float*)d_in[19]};
    const float* b2[3] = {(const float*)d_in[12], (const float*)d_in[16], (const float*)d_in[20]};
    const float* Wq = (const float*)d_in[21], *bq = (const float*)d_in[22];
    const float* Wk = (const float*)d_in[23], *bk = (const float*)d_in[24];
    const float* Wv = (const float*)d_in[25], *bv = (const float*)d_in[26];
    const float* Wo = (const float*)d_in[27], *bo = (const float*)d_in[28];
    const float* Wd = (const float*)d_in[29], *bd = (const float*)d_in[30];
    const float* Wfc = (const float*)d_in[31], *bfc = (const float*)d_in[32];
    float* out = (float*)d_out;

    // ---- workspace carve ----
    char* p = (char*)d_ws;
    auto alloc = [&](size_t bytes) { void* r = (void*)p; p += (bytes + 255) & ~(size_t)255; return r; };
    // [embs_b | T1b | Tmid_b] contiguous 57.6 MB; QKVb (54 MB) aliases it post-GCN
    unsigned short* embs_b = (unsigned short*)alloc((size_t)V_NODES * KP * 2);  // 19.2 MB
    unsigned short* T1b    = (unsigned short*)alloc((size_t)V_NODES * KP * 2);  // 19.2 MB
    unsigned short* Tmidb  = (unsigned short*)alloc((size_t)V_NODES * KP * 2);  // 19.2 MB
    unsigned short* QKVb   = embs_b;   // [3][CM][900] bf16 = 54 MB <= 57.6 MB

    unsigned short* omb = (unsigned short*)alloc((size_t)V_NODES * KP * 2);     // 19.2 MB

    float* ns3   = (float*)alloc((size_t)3 * V_NODES * 4);
    float* nd3   = (float*)alloc((size_t)3 * V_NODES * 4);
    float* ndns3 = (float*)alloc((size_t)3 * V_NODES * 4);
    float* dhat3 = (float*)alloc((size_t)3 * V_NODES * 4);
    int* degs    = (int*)alloc((size_t)9 * V_NODES * 4);   // deg0|deg1 (x3) + cursors(x3)
    int* cursors = degs + 6 * V_NODES;
    int* row_ptr3 = (int*)alloc((size_t)3 * (V_NODES + 1) * 4);
    int* col3     = (int*)alloc((size_t)3 * NE * 4);

    float* Wdf   = (float*)alloc(300 * 20 * 4);
    float* Wcomb = (float*)alloc(300 * 20 * 4);
    float* v1    = (float*)alloc(20 * 4);
    float* v2    = (float*)alloc(20 * 4);
    float* b1w2  = (float*)alloc(300 * 4);
    float* bqkv  = (float*)alloc(NQKV * 4);
    float* W12   = (float*)alloc(300 * 300 * 4);
    unsigned short* W12b  = (unsigned short*)alloc(300 * KP * 2);
    unsigned short* Wqkvb = (unsigned short*)alloc((size_t)NQKV * KP * 2);

    unsigned short* Bvs_b[3];
    for (int i = 0; i < 3; i++)
        Bvs_b[i] = (unsigned short*)alloc((size_t)V_NODES * KP * 2);            // 3x19.2 MB
    float* DM = (float*)Bvs_b[0];   // [NDOCS][300] fp32 = 9.8 MB (Bvs free post-QKV)
    float* DC = (float*)Bvs_b[1];

    auto bgemm = [&](const unsigned short* ab, const unsigned short* bb,
                     float* cf, unsigned short* cb, int M, int N, int ldc,
                     const float* bias, const float* rowscale) {
        dim3 grid((N + GBN - 1) / GBN, (M + GBM - 1) / GBM);
        hipLaunchKernelGGL(bgemm_kernel, grid, dim3(256), 0, stream,
                           ab, bb, cf, cb, M, N, ldc, bias, rowscale);
    };
    auto sgemm = [&](const float* A, const float* B, float* C, int M, int N, int K,
                     const float* bias, const float* rowv = nullptr, const float* colv = nullptr) {
        dim3 grid((N + BN - 1) / BN, (M + BM - 1) / BM);
        hipLaunchKernelGGL(sgemm_kernel, grid, dim3(256), 0, stream,
                           A, B, C, M, N, K, bias, rowv, colv);
    };

    const int EB = (NE + 255) / 256;
    const int VB = (V_NODES + 255) / 256;

    // ---- one-time prep ----
    sgemm(Wd, Wfc, Wdf, DIM, 20, DIM, nullptr);            // Wd@Wfc
    sgemm(Wo, Wdf, Wcomb, DIM, 20, DIM, nullptr);          // Wo@Wd@Wfc
    sgemm(bo, Wdf, v1, 1, 20, DIM, nullptr);               // bo@Wd@Wfc
    sgemm(bd, Wfc, v2, 1, 20, DIM, bfc);                   // bd@Wfc+bfc
    hipLaunchKernelGGL(concat3_kernel, dim3(4), dim3(256), 0, stream, bq, bk, bv, bqkv);
    hipLaunchKernelGGL(splitb_w_kernel, dim3(300), dim3(KP), 0, stream, Wq, 300, 0,   Wqkvb);
    hipLaunchKernelGGL(splitb_w_kernel, dim3(300), dim3(KP), 0, stream, Wk, 300, 300, Wqkvb);
    hipLaunchKernelGGL(splitb_w_kernel, dim3(300), dim3(KP), 0, stream, Wv, 300, 600, Wqkvb);
    hipLaunchKernelGGL(splitb_a_kernel, dim3(V_NODES), dim3(KP), 0, stream, emb, embs_b);

    // ---- fused graph prep for all 3 branches ----
    hipMemsetAsync(degs, 0, (size_t)9 * V_NODES * 4, stream);
    hipLaunchKernelGGL(degree3_kernel, dim3(EB, 3), dim3(256), 0, stream,
                       srcs[0], dsts[0], srcs[1], dsts[1], srcs[2], dsts[2], degs);
    hipLaunchKernelGGL(nsnd3_kernel, dim3(VB, 3), dim3(256), 0, stream, degs, ns3, nd3, ndns3);
    hipLaunchKernelGGL(scan3_kernel, dim3(3), dim3(1024), 0, stream, degs, row_ptr3);
    hipLaunchKernelGGL(fill3_kernel, dim3(EB, 3), dim3(256), 0, stream,
                       srcs[0], dsts[0], srcs[1], dsts[1], srcs[2], dsts[2],
                       row_ptr3, cursors, col3);
    hipLaunchKernelGGL(dhat3_kernel, dim3(VB, 3), dim3(256), 0, stream,
                       row_ptr3, col3, ns3, nd3, dhat3);

    // ---- three GCN branches (layers folded: nd⊙A(ndns⊙A(ns⊙(X W12))) + dhat⊗(b1W2) + b2 + X) ----
    for (int br = 0; br < 3; br++) {
        const int* row_ptr = row_ptr3 + br * (V_NODES + 1);
        const int* col = col3 + (size_t)br * NE;
        const float* ns = ns3 + br * V_NODES;
        const float* nd = nd3 + br * V_NODES;
        const float* ndns = ndns3 + br * V_NODES;
        const float* dhat = dhat3 + br * V_NODES;

        sgemm(W1[br], W2[br], W12, DIM, DIM, DIM, nullptr);           // W12 = W1@W2
        sgemm(b1[br], W2[br], b1w2, 1, DIM, DIM, nullptr);            // b1@W2
        hipLaunchKernelGGL(splitb_w_kernel, dim3(300), dim3(KP), 0, stream, W12, 300, 0, W12b);

        // T1b = bf16( ns ⊙ (emb @ W12) )
        bgemm(embs_b, W12b, nullptr, T1b, V_NODES, DIM, KP, nullptr, ns);
        // Tmidb = bf16( ndns ⊙ A(T1b) )
        hipLaunchKernelGGL(agg_kernel, dim3(V_NODES), dim3(320), 0, stream,
                           T1b, row_ptr, col, ndns,
                           (const float*)nullptr, (const float*)nullptr,
                           (const float*)nullptr, (const float*)nullptr, Tmidb);
        // Bvs[br] = bf16( nd ⊙ A(Tmidb) + dhat⊗b1w2 + b2 + emb )
        hipLaunchKernelGGL(agg_kernel, dim3(V_NODES), dim3(320), 0, stream,
                           Tmidb, row_ptr, col, nd, b2[br], dhat, b1w2, emb, Bvs_b[br]);
    }

    // ---- QKV + attention (chunked; QKVb aliases embs/T1b/Tmidb, all dead now) ----
    for (int c = 0; c < V_NODES / CM; c++) {
        int r0 = c * CM;
        for (int s = 0; s < 3; s++) {
            bgemm(Bvs_b[s] + (size_t)r0 * KP, Wqkvb,
                  nullptr, QKVb + (size_t)s * CM * NQKV, CM, NQKV, NQKV, bqkv, nullptr);
        }
        hipLaunchKernelGGL(attn_kernel, dim3((CM * 30 + 255) / 256), dim3(256), 0, stream,
                           QKVb, omb, CM, r0);
    }

    // ---- doc pipeline (folded tail) ----
    hipLaunchKernelGGL(docmean_kernel, dim3(NDOCS), dim3(320), 0, stream, omb, adj, DM, DC);
    sgemm(DM, Wcomb, out, NDOCS, 20, DIM, v2, DC, v1);   // out = DM@Wcomb + DC⊗v1 + v2
}